// Round 5
// baseline (327.799 us; speedup 1.0000x reference)
//
#include <hip/hip_runtime.h>

#define N_NODES 50000
#define E_EDGES 800000
#define D 256
#define L 128
#define CAP 64   // max in-degree bucket capacity; Poisson(16) tail => P(overflow) ~ 1e-19

typedef __attribute__((ext_vector_type(8))) short bf16x8;
typedef __attribute__((ext_vector_type(4))) float f32x4;

__device__ __forceinline__ float bf2f(unsigned short u) {
    union { unsigned int i; float f; } v; v.i = ((unsigned int)u) << 16; return v.f;
}
__device__ __forceinline__ unsigned short f2bf(float f) {  // round-to-nearest-even
    union { float f; unsigned int i; } v; v.f = f;
    unsigned int r = v.i + 0x7fffu + ((v.i >> 16) & 1u);
    return (unsigned short)(r >> 16);
}

// Single-pass bucket build: cursor ends up = in-degree.
__global__ __launch_bounds__(256) void fill_fixed(const int* __restrict__ src,
                                                  const int* __restrict__ dst,
                                                  int* __restrict__ cursor,
                                                  int* __restrict__ bucket) {
    int e = blockIdx.x * 256 + threadIdx.x;
    if (e >= E_EDGES) return;
    int d = dst[e];
    int pos = atomicAdd(&cursor[d], 1);
    if (pos < CAP) bucket[d * CAP + pos] = src[e];
}

// Fused setup: blocks 0..255 transpose/split W1; 256..511 transpose/split
// Wcat=[Wmu|Wlv] (block 256 also fills bcat); 512..707 zero the cursor.
__global__ __launch_bounds__(256) void setup(
    const float* __restrict__ W1, const float* __restrict__ Wmu,
    const float* __restrict__ Wlv, const float* __restrict__ bmu,
    const float* __restrict__ blv,
    unsigned short* __restrict__ W1h, unsigned short* __restrict__ W1l,
    unsigned short* __restrict__ Wch, unsigned short* __restrict__ Wcl,
    float* __restrict__ bcat, int* __restrict__ cursor) {
    int b = blockIdx.x, t = threadIdx.x;
    if (b < 256) {
        int n = b, k = t;
        float w = W1[k * 256 + n];
        unsigned short h = f2bf(w);
        W1h[n * 256 + k] = h;
        W1l[n * 256 + k] = f2bf(w - bf2f(h));
    } else if (b < 512) {
        int n = b - 256, k = t;
        float w = (n < 128) ? Wmu[k * 128 + n] : Wlv[k * 128 + (n - 128)];
        unsigned short h = f2bf(w);
        Wch[n * 256 + k] = h;
        Wcl[n * 256 + k] = f2bf(w - bf2f(h));
        if (b == 256) bcat[t] = (t < 128) ? bmu[t] : blv[t - 128];
    } else {
        int i = (b - 512) * 256 + t;
        if (i < N_NODES) cursor[i] = 0;
    }
}

// MFMA GEMM (layer 1): H[M,256] = X_f32[M,256] @ (Bh+Bl)[256,256], fp32-split
// 3-term. Block = 64 rows x 256 cols, 4 waves 2x2 (each 32 rows x 128 cols).
// Grid 782 ~= 3.05 blocks/CU (balanced; 3 resident for cross-block overlap).
// Rotated loop: global loads for step k+1 issue BEFORE MFMA(k) so the A-stream
// drain at the next barrier overlaps compute. LDS 40 KB, XOR-chunk swizzle
// (0 bank conflicts, verified in ancestors).
__global__ __launch_bounds__(256, 3) void gemm_mfma(
    const float* __restrict__ A,
    const unsigned short* __restrict__ Bth, const unsigned short* __restrict__ Btl,
    unsigned short* __restrict__ Hout, int M)
{
    __shared__ unsigned short Ash[64 * 32];    // 4 KB
    __shared__ unsigned short Asl[64 * 32];    // 4 KB
    __shared__ unsigned short Bsh[256 * 32];   // 16 KB
    __shared__ unsigned short Bsl[256 * 32];   // 16 KB
    const int t = threadIdx.x;
    const int lane = t & 63, wave = t >> 6;
    const int m_ = lane & 15, q = lane >> 4;
    const int wr = wave >> 1, wc = wave & 1;   // 2x2 wave grid
    const int row0 = blockIdx.x * 64;
    const int sr = t >> 2;                     // staging row 0..63
    const int sc = t & 3;                      // staging chunk 0..3

    int rA = row0 + sr; if (rA >= M) rA = M - 1;
    const float* Ap = A + (size_t)rA * 256;

    f32x4 acc[2][8];
    const f32x4 zf = {0.f, 0.f, 0.f, 0.f};
#pragma unroll
    for (int rs = 0; rs < 2; ++rs)
#pragma unroll
        for (int nt = 0; nt < 8; ++nt) acc[rs][nt] = zf;

    // preload k=0
    bf16x8 gbh[4], gbl[4];
    float4 ga0, ga1;
#pragma unroll
    for (int i = 0; i < 4; ++i) {
        int n = sr + i * 64;
        gbh[i] = *(const bf16x8*)(Bth + n * 256 + sc * 8);
        gbl[i] = *(const bf16x8*)(Btl + n * 256 + sc * 8);
    }
    ga0 = *(const float4*)(Ap + sc * 8);
    ga1 = *(const float4*)(Ap + sc * 8 + 4);

    for (int ks = 0; ks < 8; ++ks) {
        __syncthreads();   // all waves done reading the buffer (prev step)
        // stage writes (compiler waits the loads here)
        {
            int cc = (sc ^ ((sr >> 1) & 3)) * 8;
            float af[8] = {ga0.x, ga0.y, ga0.z, ga0.w, ga1.x, ga1.y, ga1.z, ga1.w};
            bf16x8 h, l;
#pragma unroll
            for (int j = 0; j < 8; ++j) {
                unsigned short hh = f2bf(af[j]);
                h[j] = (short)hh;
                l[j] = (short)f2bf(af[j] - bf2f(hh));
            }
            *(bf16x8*)&Ash[sr * 32 + cc] = h;
            *(bf16x8*)&Asl[sr * 32 + cc] = l;
        }
#pragma unroll
        for (int i = 0; i < 4; ++i) {
            int n = sr + i * 64;
            int cc = (sc ^ ((n >> 1) & 3)) * 8;
            *(bf16x8*)&Bsh[n * 32 + cc] = gbh[i];
            *(bf16x8*)&Bsl[n * 32 + cc] = gbl[i];
        }
        __syncthreads();   // buffer ready
        // issue next step's global loads now — they drain during MFMA below
        if (ks < 7) {
            const int k1 = (ks + 1) * 32;
#pragma unroll
            for (int i = 0; i < 4; ++i) {
                int n = sr + i * 64;
                gbh[i] = *(const bf16x8*)(Bth + n * 256 + k1 + sc * 8);
                gbl[i] = *(const bf16x8*)(Btl + n * 256 + k1 + sc * 8);
            }
            ga0 = *(const float4*)(Ap + k1 + sc * 8);
            ga1 = *(const float4*)(Ap + k1 + sc * 8 + 4);
        }
        // fragment reads + MFMA
        bf16x8 ah[2], al[2];
#pragma unroll
        for (int rs = 0; rs < 2; ++rs) {
            int r = wr * 32 + rs * 16 + m_;
            int cc = (q ^ ((r >> 1) & 3)) * 8;
            ah[rs] = *(const bf16x8*)&Ash[r * 32 + cc];
            al[rs] = *(const bf16x8*)&Asl[r * 32 + cc];
        }
#pragma unroll
        for (int nt = 0; nt < 8; ++nt) {
            int n = wc * 128 + nt * 16 + m_;
            int cr = (q ^ ((n >> 1) & 3)) * 8;
            bf16x8 bh = *(const bf16x8*)&Bsh[n * 32 + cr];
            bf16x8 bl = *(const bf16x8*)&Bsl[n * 32 + cr];
#pragma unroll
            for (int rs = 0; rs < 2; ++rs) {
                acc[rs][nt] = __builtin_amdgcn_mfma_f32_16x16x32_bf16(ah[rs], bh, acc[rs][nt], 0, 0, 0);
                acc[rs][nt] = __builtin_amdgcn_mfma_f32_16x16x32_bf16(ah[rs], bl, acc[rs][nt], 0, 0, 0);
                acc[rs][nt] = __builtin_amdgcn_mfma_f32_16x16x32_bf16(al[rs], bh, acc[rs][nt], 0, 0, 0);
            }
        }
    }
    // epilogue: C/D layout col=lane&15, row=(lane>>4)*4+reg  [m89/m91 verified]
#pragma unroll
    for (int rs = 0; rs < 2; ++rs) {
        int rbase = row0 + wr * 32 + rs * 16 + q * 4;
#pragma unroll
        for (int rr = 0; rr < 4; ++rr) {
            int grow = rbase + rr;
            if (grow >= M) continue;
#pragma unroll
            for (int nt = 0; nt < 8; ++nt) {
                int gcol = wc * 128 + nt * 16 + m_;
                Hout[(size_t)grow * 256 + gcol] = f2bf(acc[rs][nt][rr]);
            }
        }
    }
}

// MFMA GEMM (head): T[M,256] = Z_bf16[M,256] @ (Bh+Bl)[256,256], 2-term (A is
// exact bf16). Same 64x256 block / 2x2 wave / rotated-loop structure. LDS 36 KB.
__global__ __launch_bounds__(256, 3) void gemm_bf16(
    const unsigned short* __restrict__ A,
    const unsigned short* __restrict__ Bth, const unsigned short* __restrict__ Btl,
    unsigned short* __restrict__ Tout, int M)
{
    __shared__ unsigned short Ash[64 * 32];    // 4 KB
    __shared__ unsigned short Bsh[256 * 32];   // 16 KB
    __shared__ unsigned short Bsl[256 * 32];   // 16 KB
    const int t = threadIdx.x;
    const int lane = t & 63, wave = t >> 6;
    const int m_ = lane & 15, q = lane >> 4;
    const int wr = wave >> 1, wc = wave & 1;
    const int row0 = blockIdx.x * 64;
    const int sr = t >> 2;
    const int sc = t & 3;

    int rA = row0 + sr; if (rA >= M) rA = M - 1;
    const unsigned short* Ap = A + (size_t)rA * 256;

    f32x4 acc[2][8];
    const f32x4 zf = {0.f, 0.f, 0.f, 0.f};
#pragma unroll
    for (int rs = 0; rs < 2; ++rs)
#pragma unroll
        for (int nt = 0; nt < 8; ++nt) acc[rs][nt] = zf;

    bf16x8 gbh[4], gbl[4], gav;
#pragma unroll
    for (int i = 0; i < 4; ++i) {
        int n = sr + i * 64;
        gbh[i] = *(const bf16x8*)(Bth + n * 256 + sc * 8);
        gbl[i] = *(const bf16x8*)(Btl + n * 256 + sc * 8);
    }
    gav = *(const bf16x8*)(Ap + sc * 8);

    for (int ks = 0; ks < 8; ++ks) {
        __syncthreads();
        {
            int cc = (sc ^ ((sr >> 1) & 3)) * 8;
            *(bf16x8*)&Ash[sr * 32 + cc] = gav;
        }
#pragma unroll
        for (int i = 0; i < 4; ++i) {
            int n = sr + i * 64;
            int cc = (sc ^ ((n >> 1) & 3)) * 8;
            *(bf16x8*)&Bsh[n * 32 + cc] = gbh[i];
            *(bf16x8*)&Bsl[n * 32 + cc] = gbl[i];
        }
        __syncthreads();
        if (ks < 7) {
            const int k1 = (ks + 1) * 32;
#pragma unroll
            for (int i = 0; i < 4; ++i) {
                int n = sr + i * 64;
                gbh[i] = *(const bf16x8*)(Bth + n * 256 + k1 + sc * 8);
                gbl[i] = *(const bf16x8*)(Btl + n * 256 + k1 + sc * 8);
            }
            gav = *(const bf16x8*)(Ap + k1 + sc * 8);
        }
        bf16x8 ah[2];
#pragma unroll
        for (int rs = 0; rs < 2; ++rs) {
            int r = wr * 32 + rs * 16 + m_;
            int cc = (q ^ ((r >> 1) & 3)) * 8;
            ah[rs] = *(const bf16x8*)&Ash[r * 32 + cc];
        }
#pragma unroll
        for (int nt = 0; nt < 8; ++nt) {
            int n = wc * 128 + nt * 16 + m_;
            int cr = (q ^ ((n >> 1) & 3)) * 8;
            bf16x8 bh = *(const bf16x8*)&Bsh[n * 32 + cr];
            bf16x8 bl = *(const bf16x8*)&Bsl[n * 32 + cr];
#pragma unroll
            for (int rs = 0; rs < 2; ++rs) {
                acc[rs][nt] = __builtin_amdgcn_mfma_f32_16x16x32_bf16(ah[rs], bh, acc[rs][nt], 0, 0, 0);
                acc[rs][nt] = __builtin_amdgcn_mfma_f32_16x16x32_bf16(ah[rs], bl, acc[rs][nt], 0, 0, 0);
            }
        }
    }
#pragma unroll
    for (int rs = 0; rs < 2; ++rs) {
        int rbase = row0 + wr * 32 + rs * 16 + q * 4;
#pragma unroll
        for (int rr = 0; rr < 4; ++rr) {
            int grow = rbase + rr;
            if (grow >= M) continue;
#pragma unroll
            for (int nt = 0; nt < 8; ++nt) {
                int gcol = wc * 128 + nt * 16 + m_;
                Tout[(size_t)grow * 256 + gcol] = f2bf(acc[rs][nt][rr]);
            }
        }
    }
}

// Two dst nodes per wave: each 32-lane half owns one node, 8 bf16 cols/lane
// (16 B loads; one full 512 B row per half-wave memory op). Edge metadata
// preloaded into lane registers, broadcast per-edge via __shfl with the
// half-select bit (lane&32). [r1/r3/r4-verified ~63 us / 190 MB fetch — at the
// random-gather L2-miss-path floor (~3 TB/s).] dinv computed on the fly from
// cursor counts (rsqrtf, bit-identical to the old dinv_fin values).
// mode 0: Z = relu(agg + b1) -> bf16.
// mode 1: final heads: [mu|lv] = agg(T) + bcat -> fp32, split at col 128.
__global__ __launch_bounds__(256) void gather_pre(
    const unsigned short* __restrict__ Hs,
    const int* __restrict__ bucket, const int* __restrict__ cnt_,
    const float* __restrict__ bias,
    unsigned short* __restrict__ OutZ,
    float* __restrict__ mu, float* __restrict__ lv, int mode)
{
    const int lane = threadIdx.x & 63;
    const int hl = lane & 31;                 // lane within half-wave
    const int bb = lane & 32;                 // half-select for shfl index
    const int node = blockIdx.x * 8 + (threadIdx.x >> 5);   // 8 nodes/block
    const int col = hl * 8;                   // 8 bf16 columns per lane
    int raw = cnt_[node];
    float dn = rsqrtf((float)raw + 1.0f);
    int cnt = raw > CAP ? CAP : raw;

    // preload: half-lane j owns edge j (reg0) and edge j+32 (reg1)
    int   s0r = 0, s1r = 0;
    float w0r = 0.f, w1r = 0.f;
    if (hl < cnt) {
        s0r = bucket[node * CAP + hl];
        w0r = rsqrtf((float)cnt_[s0r] + 1.0f) * dn;
    }
    if (hl + 32 < cnt) {
        s1r = bucket[node * CAP + 32 + hl];
        w1r = rsqrtf((float)cnt_[s1r] + 1.0f) * dn;
    }

    // start accumulator with the self-loop term (norm_ii = 1/deg = dn*dn)
    float sl = dn * dn;
    bf16x8 hv = *(const bf16x8*)(Hs + (size_t)node * D + col);
    float a[8];
#pragma unroll
    for (int p = 0; p < 8; ++p) a[p] = bf2f((unsigned short)hv[p]) * sl;

    const int cnt0 = cnt < 32 ? cnt : 32;
    int j = 0;
    for (; j + 3 < cnt0; j += 4) {
        int t0 = __shfl(s0r, bb + j,     64), t1 = __shfl(s0r, bb + j + 1, 64);
        int t2 = __shfl(s0r, bb + j + 2, 64), t3 = __shfl(s0r, bb + j + 3, 64);
        float w0 = __shfl(w0r, bb + j,     64), w1 = __shfl(w0r, bb + j + 1, 64);
        float w2 = __shfl(w0r, bb + j + 2, 64), w3 = __shfl(w0r, bb + j + 3, 64);
        bf16x8 u0 = *(const bf16x8*)(Hs + (size_t)t0 * D + col);
        bf16x8 u1 = *(const bf16x8*)(Hs + (size_t)t1 * D + col);
        bf16x8 u2 = *(const bf16x8*)(Hs + (size_t)t2 * D + col);
        bf16x8 u3 = *(const bf16x8*)(Hs + (size_t)t3 * D + col);
#pragma unroll
        for (int p = 0; p < 8; ++p) a[p] = fmaf(bf2f((unsigned short)u0[p]), w0, a[p]);
#pragma unroll
        for (int p = 0; p < 8; ++p) a[p] = fmaf(bf2f((unsigned short)u1[p]), w1, a[p]);
#pragma unroll
        for (int p = 0; p < 8; ++p) a[p] = fmaf(bf2f((unsigned short)u2[p]), w2, a[p]);
#pragma unroll
        for (int p = 0; p < 8; ++p) a[p] = fmaf(bf2f((unsigned short)u3[p]), w3, a[p]);
    }
    for (; j < cnt0; ++j) {
        int   t0 = __shfl(s0r, bb + j, 64);
        float w0 = __shfl(w0r, bb + j, 64);
        bf16x8 u0 = *(const bf16x8*)(Hs + (size_t)t0 * D + col);
#pragma unroll
        for (int p = 0; p < 8; ++p) a[p] = fmaf(bf2f((unsigned short)u0[p]), w0, a[p]);
    }
    if (cnt > 32) {               // Poisson(16) tail: rare
        for (int j2 = 0; j2 < cnt - 32; ++j2) {
            int   t0 = __shfl(s1r, bb + j2, 64);
            float w0 = __shfl(w1r, bb + j2, 64);
            bf16x8 u0 = *(const bf16x8*)(Hs + (size_t)t0 * D + col);
#pragma unroll
            for (int p = 0; p < 8; ++p) a[p] = fmaf(bf2f((unsigned short)u0[p]), w0, a[p]);
        }
    }

    float4 b0 = *(const float4*)(bias + col);
    float4 b1 = *(const float4*)(bias + col + 4);
    float bf[8] = {b0.x, b0.y, b0.z, b0.w, b1.x, b1.y, b1.z, b1.w};
    if (mode == 0) {
        bf16x8 o;
#pragma unroll
        for (int p = 0; p < 8; ++p) o[p] = (short)f2bf(fmaxf(a[p] + bf[p], 0.f));
        *(bf16x8*)(OutZ + (size_t)node * D + col) = o;
    } else {
        float4 o0, o1;
        o0.x = a[0] + bf[0]; o0.y = a[1] + bf[1];
        o0.z = a[2] + bf[2]; o0.w = a[3] + bf[3];
        o1.x = a[4] + bf[4]; o1.y = a[5] + bf[5];
        o1.z = a[6] + bf[6]; o1.w = a[7] + bf[7];
        // col multiple of 8; 8 cols stay within one head (128 % 8 == 0)
        float* Op = (col < 128) ? (mu + (size_t)node * L + col)
                                : (lv + (size_t)node * L + (col - 128));
        *(float4*)Op = o0;
        *(float4*)(Op + 4) = o1;
    }
}

extern "C" void kernel_launch(void* const* d_in, const int* in_sizes, int n_in,
                              void* d_out, int out_size, void* d_ws, size_t ws_size,
                              hipStream_t stream) {
    const float* x   = (const float*)d_in[0];
    const int*   ei  = (const int*)d_in[1];
    const float* W1  = (const float*)d_in[2];
    const float* b1  = (const float*)d_in[3];
    const float* Wmu = (const float*)d_in[4];
    const float* bmu = (const float*)d_in[5];
    const float* Wlv = (const float*)d_in[6];
    const float* blv = (const float*)d_in[7];
    const int* src = ei;
    const int* dst = ei + E_EDGES;

    const size_t NF = (size_t)N_NODES * D;  // 12.8M
    unsigned short* Hb = (unsigned short*)d_ws;   // [N,256] bf16
    unsigned short* Z  = Hb + NF;                 // [N,256] bf16
    unsigned short* T  = Z + NF;                  // [N,256] bf16 = Z @ [Wmu|Wlv]
    unsigned short* W1h = T + NF;
    unsigned short* W1l = W1h + 65536;
    unsigned short* Wch = W1l + 65536;
    unsigned short* Wcl = Wch + 65536;
    float* bcat = (float*)(Wcl + 65536);
    int* cursor = (int*)(bcat + 256);
    int* bucket = cursor + N_NODES;          // [N*CAP]
    float* mu = (float*)d_out;
    float* lv = mu + (size_t)N_NODES * L;

    // setup: weight transpose/split + cursor zeroing in one launch
    setup<<<512 + (N_NODES + 255) / 256, 256, 0, stream>>>(
        W1, Wmu, Wlv, bmu, blv, W1h, W1l, Wch, Wcl, bcat, cursor);
    // graph build: one atomic pass, degrees land in cursor
    fill_fixed<<<(E_EDGES + 255) / 256, 256, 0, stream>>>(src, dst, cursor, bucket);

    const int gemm_blocks = (N_NODES + 63) / 64;     // 782 ~= 3.05 blocks/CU
    const int gat_blocks  = N_NODES / 8;             // 6250 (50000 % 8 == 0)
    // layer 1: H = X@W1 (bf16 out)
    gemm_mfma<<<gemm_blocks, 256, 0, stream>>>(x, W1h, W1l, Hb, N_NODES);
    // Z = relu(P·H + b1)
    gather_pre<<<gat_blocks, 256, 0, stream>>>(Hb, bucket, cursor, b1,
                                               Z, nullptr, nullptr, 0);
    // T = Z @ [Wmu|Wlv]  (bf16; P commutes with right-multiplication)
    gemm_bf16<<<gemm_blocks, 256, 0, stream>>>(Z, Wch, Wcl, T, N_NODES);
    // [mu|lv] = P·T + [bmu|blv]  (fp32, direct to output)
    gather_pre<<<gat_blocks, 256, 0, stream>>>(T, bucket, cursor, bcat,
                                               nullptr, mu, lv, 1);
}

// Round 6
// 321.160 us; speedup vs baseline: 1.0207x; 1.0207x over previous
//
#include <hip/hip_runtime.h>

#define N_NODES 50000
#define E_EDGES 800000
#define D 256
#define L 128
#define CAP 64   // max in-degree bucket capacity; Poisson(16) tail => P(overflow) ~ 1e-19

typedef __attribute__((ext_vector_type(8))) short bf16x8;
typedef __attribute__((ext_vector_type(4))) float f32x4;

__device__ __forceinline__ float bf2f(unsigned short u) {
    union { unsigned int i; float f; } v; v.i = ((unsigned int)u) << 16; return v.f;
}
__device__ __forceinline__ unsigned short f2bf(float f) {  // round-to-nearest-even
    union { float f; unsigned int i; } v; v.f = f;
    unsigned int r = v.i + 0x7fffu + ((v.i >> 16) & 1u);
    return (unsigned short)(r >> 16);
}

// Single-pass bucket build: cursor ends up = in-degree.
__global__ __launch_bounds__(256) void fill_fixed(const int* __restrict__ src,
                                                  const int* __restrict__ dst,
                                                  int* __restrict__ cursor,
                                                  int* __restrict__ bucket) {
    int e = blockIdx.x * 256 + threadIdx.x;
    if (e >= E_EDGES) return;
    int d = dst[e];
    int pos = atomicAdd(&cursor[d], 1);
    if (pos < CAP) bucket[d * CAP + pos] = src[e];
}

// Setup with LDS-tiled transpose (coalesced on BOTH sides; old version read
// W at stride-256 fp32 = 64 lines/wave-instr). Blocks 0..63: W1 tiles;
// 64..127: Wcat=[Wmu|Wlv] tiles (block 64 also fills bcat); rest zero cursor.
__global__ __launch_bounds__(256) void setup_t(
    const float* __restrict__ W1, const float* __restrict__ Wmu,
    const float* __restrict__ Wlv, const float* __restrict__ bmu,
    const float* __restrict__ blv,
    unsigned short* __restrict__ W1h, unsigned short* __restrict__ W1l,
    unsigned short* __restrict__ Wch, unsigned short* __restrict__ Wcl,
    float* __restrict__ bcat, int* __restrict__ cursor) {
    int b = blockIdx.x, t = threadIdx.x;
    if (b < 128) {
        __shared__ float tile[32][33];          // +1 pad: conflict-free transpose
        int m = b >> 6;                         // 0: W1, 1: Wcat
        int ti = b & 63;
        int k0 = (ti >> 3) * 32, n0 = (ti & 7) * 32;
        int rr = t >> 5, cc = t & 31;           // 8 rows x 32 cols per pass
#pragma unroll
        for (int p = 0; p < 4; ++p) {           // load 32x32 fp32, coalesced in n
            int kk = p * 8 + rr;
            int k = k0 + kk, n = n0 + cc;
            float w;
            if (m == 0) w = W1[k * 256 + n];
            else        w = (n < 128) ? Wmu[k * 128 + n] : Wlv[k * 128 + (n - 128)];
            tile[kk][cc] = w;
        }
        __syncthreads();
        unsigned short* Wh = (m == 0) ? W1h : Wch;
        unsigned short* Wl = (m == 0) ? W1l : Wcl;
#pragma unroll
        for (int p = 0; p < 4; ++p) {           // store [n][k], coalesced in k
            int nn = p * 8 + rr;
            float w = tile[cc][nn];
            unsigned short h = f2bf(w);
            int n = n0 + nn, k = k0 + cc;
            Wh[n * 256 + k] = h;
            Wl[n * 256 + k] = f2bf(w - bf2f(h));
        }
        if (b == 64) bcat[t] = (t < 128) ? bmu[t] : blv[t - 128];
    } else {
        int i = (b - 128) * 256 + t;
        if (i < N_NODES) cursor[i] = 0;
    }
}

// MFMA GEMM (layer 1): H[M,256] = X_f32[M,256] @ (Bh+Bl)[256,256], fp32-split
// 3-term. Block = 128 rows x 256 cols, 4 waves 2x2 (each 64 rows x 128 cols).
// [r4-verified best structure: 24 ds_read_b128 -> 96 MFMA per wave per K-step.]
__global__ __launch_bounds__(256, 2) void gemm_mfma(
    const float* __restrict__ A,
    const unsigned short* __restrict__ Bth, const unsigned short* __restrict__ Btl,
    unsigned short* __restrict__ Hout, int M)
{
    __shared__ unsigned short Ash[128 * 32];   // 8 KB
    __shared__ unsigned short Asl[128 * 32];   // 8 KB
    __shared__ unsigned short Bsh[256 * 32];   // 16 KB
    __shared__ unsigned short Bsl[256 * 32];   // 16 KB
    const int t = threadIdx.x;
    const int lane = t & 63, wave = t >> 6;
    const int m_ = lane & 15, q = lane >> 4;
    const int wr = wave >> 1, wc = wave & 1;   // 2x2 wave grid
    const int row0 = blockIdx.x * 128;
    const int sr = t >> 2;                     // staging row 0..63
    const int sc = t & 3;                      // staging chunk 0..3

    f32x4 acc[4][8];
    const f32x4 zf = {0.f, 0.f, 0.f, 0.f};
#pragma unroll
    for (int rs = 0; rs < 4; ++rs)
#pragma unroll
        for (int nt = 0; nt < 8; ++nt) acc[rs][nt] = zf;

    for (int ks = 0; ks < 8; ++ks) {
        const int k0 = ks * 32;
        // global loads: B tile (256n x 32k, hi+lo) and A tile (128 rows fp32)
        bf16x8 gbh[4], gbl[4];
#pragma unroll
        for (int i = 0; i < 4; ++i) {
            int n = sr + i * 64;
            gbh[i] = *(const bf16x8*)(Bth + n * 256 + k0 + sc * 8);
            gbl[i] = *(const bf16x8*)(Btl + n * 256 + k0 + sc * 8);
        }
        float4 ga0[2], ga1[2];
#pragma unroll
        for (int p = 0; p < 2; ++p) {
            int r = row0 + p * 64 + sr; if (r >= M) r = M - 1;
            const float* Xp = A + (size_t)r * 256 + k0 + sc * 8;
            ga0[p] = *(const float4*)Xp;
            ga1[p] = *(const float4*)(Xp + 4);
        }
        __syncthreads();
#pragma unroll
        for (int p = 0; p < 2; ++p) {
            int lr = p * 64 + sr;
            int cc = (sc ^ ((lr >> 1) & 3)) * 8;
            float af[8] = {ga0[p].x, ga0[p].y, ga0[p].z, ga0[p].w,
                           ga1[p].x, ga1[p].y, ga1[p].z, ga1[p].w};
            bf16x8 h, l;
#pragma unroll
            for (int j = 0; j < 8; ++j) {
                unsigned short hh = f2bf(af[j]);
                h[j] = (short)hh;
                l[j] = (short)f2bf(af[j] - bf2f(hh));
            }
            *(bf16x8*)&Ash[lr * 32 + cc] = h;
            *(bf16x8*)&Asl[lr * 32 + cc] = l;
        }
#pragma unroll
        for (int i = 0; i < 4; ++i) {
            int n = sr + i * 64;
            int cc = (sc ^ ((n >> 1) & 3)) * 8;
            *(bf16x8*)&Bsh[n * 32 + cc] = gbh[i];
            *(bf16x8*)&Bsl[n * 32 + cc] = gbl[i];
        }
        __syncthreads();
        // fragment reads + MFMA
        bf16x8 ah[4], al[4];
#pragma unroll
        for (int rs = 0; rs < 4; ++rs) {
            int r = wr * 64 + rs * 16 + m_;
            int cc = (q ^ ((r >> 1) & 3)) * 8;
            ah[rs] = *(const bf16x8*)&Ash[r * 32 + cc];
            al[rs] = *(const bf16x8*)&Asl[r * 32 + cc];
        }
#pragma unroll
        for (int nt = 0; nt < 8; ++nt) {
            int n = wc * 128 + nt * 16 + m_;
            int cr = (q ^ ((n >> 1) & 3)) * 8;
            bf16x8 bh = *(const bf16x8*)&Bsh[n * 32 + cr];
            bf16x8 bl = *(const bf16x8*)&Bsl[n * 32 + cr];
#pragma unroll
            for (int rs = 0; rs < 4; ++rs) {
                acc[rs][nt] = __builtin_amdgcn_mfma_f32_16x16x32_bf16(ah[rs], bh, acc[rs][nt], 0, 0, 0);
                acc[rs][nt] = __builtin_amdgcn_mfma_f32_16x16x32_bf16(ah[rs], bl, acc[rs][nt], 0, 0, 0);
                acc[rs][nt] = __builtin_amdgcn_mfma_f32_16x16x32_bf16(al[rs], bh, acc[rs][nt], 0, 0, 0);
            }
        }
    }
    // epilogue: C/D layout col=lane&15, row=(lane>>4)*4+reg  [m89/m91 verified]
#pragma unroll
    for (int rs = 0; rs < 4; ++rs) {
        int rbase = row0 + wr * 64 + rs * 16 + q * 4;
#pragma unroll
        for (int rr = 0; rr < 4; ++rr) {
            int grow = rbase + rr;
            if (grow >= M) continue;
#pragma unroll
            for (int nt = 0; nt < 8; ++nt) {
                int gcol = wc * 128 + nt * 16 + m_;
                Hout[(size_t)grow * 256 + gcol] = f2bf(acc[rs][nt][rr]);
            }
        }
    }
}

// MFMA GEMM (head): T[M,256] = Z_bf16[M,256] @ (Bh+Bl)[256,256], 2-term (A is
// exact bf16). Same 128x256 block / 2x2 wave structure. Output bf16.
__global__ __launch_bounds__(256, 2) void gemm_bf16(
    const unsigned short* __restrict__ A,
    const unsigned short* __restrict__ Bth, const unsigned short* __restrict__ Btl,
    unsigned short* __restrict__ Tout, int M)
{
    __shared__ unsigned short Ash[128 * 32];   // 8 KB
    __shared__ unsigned short Bsh[256 * 32];   // 16 KB
    __shared__ unsigned short Bsl[256 * 32];   // 16 KB
    const int t = threadIdx.x;
    const int lane = t & 63, wave = t >> 6;
    const int m_ = lane & 15, q = lane >> 4;
    const int wr = wave >> 1, wc = wave & 1;
    const int row0 = blockIdx.x * 128;
    const int sr = t >> 2;
    const int sc = t & 3;

    f32x4 acc[4][8];
    const f32x4 zf = {0.f, 0.f, 0.f, 0.f};
#pragma unroll
    for (int rs = 0; rs < 4; ++rs)
#pragma unroll
        for (int nt = 0; nt < 8; ++nt) acc[rs][nt] = zf;

    for (int ks = 0; ks < 8; ++ks) {
        const int k0 = ks * 32;
        bf16x8 gbh[4], gbl[4];
#pragma unroll
        for (int i = 0; i < 4; ++i) {
            int n = sr + i * 64;
            gbh[i] = *(const bf16x8*)(Bth + n * 256 + k0 + sc * 8);
            gbl[i] = *(const bf16x8*)(Btl + n * 256 + k0 + sc * 8);
        }
        bf16x8 gav[2];
#pragma unroll
        for (int p = 0; p < 2; ++p) {
            int r = row0 + p * 64 + sr; if (r >= M) r = M - 1;
            gav[p] = *(const bf16x8*)(A + (size_t)r * 256 + k0 + sc * 8);
        }
        __syncthreads();
#pragma unroll
        for (int p = 0; p < 2; ++p) {
            int lr = p * 64 + sr;
            int cc = (sc ^ ((lr >> 1) & 3)) * 8;
            *(bf16x8*)&Ash[lr * 32 + cc] = gav[p];
        }
#pragma unroll
        for (int i = 0; i < 4; ++i) {
            int n = sr + i * 64;
            int cc = (sc ^ ((n >> 1) & 3)) * 8;
            *(bf16x8*)&Bsh[n * 32 + cc] = gbh[i];
            *(bf16x8*)&Bsl[n * 32 + cc] = gbl[i];
        }
        __syncthreads();
        bf16x8 ah[4];
#pragma unroll
        for (int rs = 0; rs < 4; ++rs) {
            int r = wr * 64 + rs * 16 + m_;
            int cc = (q ^ ((r >> 1) & 3)) * 8;
            ah[rs] = *(const bf16x8*)&Ash[r * 32 + cc];
        }
#pragma unroll
        for (int nt = 0; nt < 8; ++nt) {
            int n = wc * 128 + nt * 16 + m_;
            int cr = (q ^ ((n >> 1) & 3)) * 8;
            bf16x8 bh = *(const bf16x8*)&Bsh[n * 32 + cr];
            bf16x8 bl = *(const bf16x8*)&Bsl[n * 32 + cr];
#pragma unroll
            for (int rs = 0; rs < 4; ++rs) {
                acc[rs][nt] = __builtin_amdgcn_mfma_f32_16x16x32_bf16(ah[rs], bh, acc[rs][nt], 0, 0, 0);
                acc[rs][nt] = __builtin_amdgcn_mfma_f32_16x16x32_bf16(ah[rs], bl, acc[rs][nt], 0, 0, 0);
            }
        }
    }
#pragma unroll
    for (int rs = 0; rs < 4; ++rs) {
        int rbase = row0 + wr * 64 + rs * 16 + q * 4;
#pragma unroll
        for (int rr = 0; rr < 4; ++rr) {
            int grow = rbase + rr;
            if (grow >= M) continue;
#pragma unroll
            for (int nt = 0; nt < 8; ++nt) {
                int gcol = wc * 128 + nt * 16 + m_;
                Tout[(size_t)grow * 256 + gcol] = f2bf(acc[rs][nt][rr]);
            }
        }
    }
}

// Two dst nodes per wave: each 32-lane half owns one node, 8 bf16 cols/lane
// (16 B loads; one full 512 B row per half-wave memory op). Edge metadata
// preloaded into lane registers, broadcast per-edge via __shfl with the
// half-select bit (lane&32). [verified ~63.5 us / 190 MB fetch across r1-r5 —
// at the random-gather L2-miss-path floor (~3 TB/s).] dinv computed on the fly
// from cursor counts (rsqrtf, bit-identical to the old dinv_fin values).
// mode 0: Z = relu(agg + b1) -> bf16.
// mode 1: final heads: [mu|lv] = agg(T) + bcat -> fp32, split at col 128.
__global__ __launch_bounds__(256) void gather_pre(
    const unsigned short* __restrict__ Hs,
    const int* __restrict__ bucket, const int* __restrict__ cnt_,
    const float* __restrict__ bias,
    unsigned short* __restrict__ OutZ,
    float* __restrict__ mu, float* __restrict__ lv, int mode)
{
    const int lane = threadIdx.x & 63;
    const int hl = lane & 31;                 // lane within half-wave
    const int bb = lane & 32;                 // half-select for shfl index
    const int node = blockIdx.x * 8 + (threadIdx.x >> 5);   // 8 nodes/block
    const int col = hl * 8;                   // 8 bf16 columns per lane
    int raw = cnt_[node];
    float dn = rsqrtf((float)raw + 1.0f);
    int cnt = raw > CAP ? CAP : raw;

    // preload: half-lane j owns edge j (reg0) and edge j+32 (reg1)
    int   s0r = 0, s1r = 0;
    float w0r = 0.f, w1r = 0.f;
    if (hl < cnt) {
        s0r = bucket[node * CAP + hl];
        w0r = rsqrtf((float)cnt_[s0r] + 1.0f) * dn;
    }
    if (hl + 32 < cnt) {
        s1r = bucket[node * CAP + 32 + hl];
        w1r = rsqrtf((float)cnt_[s1r] + 1.0f) * dn;
    }

    // start accumulator with the self-loop term (norm_ii = 1/deg = dn*dn)
    float sl = dn * dn;
    bf16x8 hv = *(const bf16x8*)(Hs + (size_t)node * D + col);
    float a[8];
#pragma unroll
    for (int p = 0; p < 8; ++p) a[p] = bf2f((unsigned short)hv[p]) * sl;

    const int cnt0 = cnt < 32 ? cnt : 32;
    int j = 0;
    for (; j + 3 < cnt0; j += 4) {
        int t0 = __shfl(s0r, bb + j,     64), t1 = __shfl(s0r, bb + j + 1, 64);
        int t2 = __shfl(s0r, bb + j + 2, 64), t3 = __shfl(s0r, bb + j + 3, 64);
        float w0 = __shfl(w0r, bb + j,     64), w1 = __shfl(w0r, bb + j + 1, 64);
        float w2 = __shfl(w0r, bb + j + 2, 64), w3 = __shfl(w0r, bb + j + 3, 64);
        bf16x8 u0 = *(const bf16x8*)(Hs + (size_t)t0 * D + col);
        bf16x8 u1 = *(const bf16x8*)(Hs + (size_t)t1 * D + col);
        bf16x8 u2 = *(const bf16x8*)(Hs + (size_t)t2 * D + col);
        bf16x8 u3 = *(const bf16x8*)(Hs + (size_t)t3 * D + col);
#pragma unroll
        for (int p = 0; p < 8; ++p) a[p] = fmaf(bf2f((unsigned short)u0[p]), w0, a[p]);
#pragma unroll
        for (int p = 0; p < 8; ++p) a[p] = fmaf(bf2f((unsigned short)u1[p]), w1, a[p]);
#pragma unroll
        for (int p = 0; p < 8; ++p) a[p] = fmaf(bf2f((unsigned short)u2[p]), w2, a[p]);
#pragma unroll
        for (int p = 0; p < 8; ++p) a[p] = fmaf(bf2f((unsigned short)u3[p]), w3, a[p]);
    }
    for (; j < cnt0; ++j) {
        int   t0 = __shfl(s0r, bb + j, 64);
        float w0 = __shfl(w0r, bb + j, 64);
        bf16x8 u0 = *(const bf16x8*)(Hs + (size_t)t0 * D + col);
#pragma unroll
        for (int p = 0; p < 8; ++p) a[p] = fmaf(bf2f((unsigned short)u0[p]), w0, a[p]);
    }
    if (cnt > 32) {               // Poisson(16) tail: rare
        for (int j2 = 0; j2 < cnt - 32; ++j2) {
            int   t0 = __shfl(s1r, bb + j2, 64);
            float w0 = __shfl(w1r, bb + j2, 64);
            bf16x8 u0 = *(const bf16x8*)(Hs + (size_t)t0 * D + col);
#pragma unroll
            for (int p = 0; p < 8; ++p) a[p] = fmaf(bf2f((unsigned short)u0[p]), w0, a[p]);
        }
    }

    float4 b0 = *(const float4*)(bias + col);
    float4 b1 = *(const float4*)(bias + col + 4);
    float bf[8] = {b0.x, b0.y, b0.z, b0.w, b1.x, b1.y, b1.z, b1.w};
    if (mode == 0) {
        bf16x8 o;
#pragma unroll
        for (int p = 0; p < 8; ++p) o[p] = (short)f2bf(fmaxf(a[p] + bf[p], 0.f));
        *(bf16x8*)(OutZ + (size_t)node * D + col) = o;
    } else {
        float4 o0, o1;
        o0.x = a[0] + bf[0]; o0.y = a[1] + bf[1];
        o0.z = a[2] + bf[2]; o0.w = a[3] + bf[3];
        o1.x = a[4] + bf[4]; o1.y = a[5] + bf[5];
        o1.z = a[6] + bf[6]; o1.w = a[7] + bf[7];
        // col multiple of 8; 8 cols stay within one head (128 % 8 == 0)
        float* Op = (col < 128) ? (mu + (size_t)node * L + col)
                                : (lv + (size_t)node * L + (col - 128));
        *(float4*)Op = o0;
        *(float4*)(Op + 4) = o1;
    }
}

extern "C" void kernel_launch(void* const* d_in, const int* in_sizes, int n_in,
                              void* d_out, int out_size, void* d_ws, size_t ws_size,
                              hipStream_t stream) {
    const float* x   = (const float*)d_in[0];
    const int*   ei  = (const int*)d_in[1];
    const float* W1  = (const float*)d_in[2];
    const float* b1  = (const float*)d_in[3];
    const float* Wmu = (const float*)d_in[4];
    const float* bmu = (const float*)d_in[5];
    const float* Wlv = (const float*)d_in[6];
    const float* blv = (const float*)d_in[7];
    const int* src = ei;
    const int* dst = ei + E_EDGES;

    const size_t NF = (size_t)N_NODES * D;  // 12.8M
    unsigned short* Hb = (unsigned short*)d_ws;   // [N,256] bf16
    unsigned short* Z  = Hb + NF;                 // [N,256] bf16
    unsigned short* T  = Z + NF;                  // [N,256] bf16 = Z @ [Wmu|Wlv]
    unsigned short* W1h = T + NF;
    unsigned short* W1l = W1h + 65536;
    unsigned short* Wch = W1l + 65536;
    unsigned short* Wcl = Wch + 65536;
    float* bcat = (float*)(Wcl + 65536);
    int* cursor = (int*)(bcat + 256);
    int* bucket = cursor + N_NODES;          // [N*CAP]
    float* mu = (float*)d_out;
    float* lv = mu + (size_t)N_NODES * L;

    // setup: tiled weight transpose/split + cursor zeroing in one launch
    setup_t<<<128 + (N_NODES + 255) / 256, 256, 0, stream>>>(
        W1, Wmu, Wlv, bmu, blv, W1h, W1l, Wch, Wcl, bcat, cursor);
    // graph build: one atomic pass, degrees land in cursor
    fill_fixed<<<(E_EDGES + 255) / 256, 256, 0, stream>>>(src, dst, cursor, bucket);

    const int gemm_blocks = (N_NODES + 127) / 128;   // 391
    const int gat_blocks  = N_NODES / 8;             // 6250 (50000 % 8 == 0)
    // layer 1: H = X@W1 (bf16 out)
    gemm_mfma<<<gemm_blocks, 256, 0, stream>>>(x, W1h, W1l, Hb, N_NODES);
    // Z = relu(P·H + b1)
    gather_pre<<<gat_blocks, 256, 0, stream>>>(Hb, bucket, cursor, b1,
                                               Z, nullptr, nullptr, 0);
    // T = Z @ [Wmu|Wlv]  (bf16; P commutes with right-multiplication)
    gemm_bf16<<<gemm_blocks, 256, 0, stream>>>(Z, Wch, Wcl, T, N_NODES);
    // [mu|lv] = P·T + [bmu|blv]  (fp32, direct to output)
    gather_pre<<<gat_blocks, 256, 0, stream>>>(T, bucket, cursor, bcat,
                                               nullptr, mu, lv, 1);
}

// Round 7
// 320.252 us; speedup vs baseline: 1.0236x; 1.0028x over previous
//
#include <hip/hip_runtime.h>

#define N_NODES 50000
#define E_EDGES 800000
#define D 256
#define L 128
#define CAP 64   // max in-degree bucket capacity; Poisson(16) tail => P(overflow) ~ 1e-19

typedef __attribute__((ext_vector_type(8))) short bf16x8;
typedef __attribute__((ext_vector_type(4))) float f32x4;

__device__ __forceinline__ float bf2f(unsigned short u) {
    union { unsigned int i; float f; } v; v.i = ((unsigned int)u) << 16; return v.f;
}
__device__ __forceinline__ unsigned short f2bf(float f) {  // round-to-nearest-even
    union { float f; unsigned int i; } v; v.f = f;
    unsigned int r = v.i + 0x7fffu + ((v.i >> 16) & 1u);
    return (unsigned short)(r >> 16);
}

// Single-pass bucket build: cursor ends up = in-degree.
__global__ __launch_bounds__(256) void fill_fixed(const int* __restrict__ src,
                                                  const int* __restrict__ dst,
                                                  int* __restrict__ cursor,
                                                  int* __restrict__ bucket) {
    int e = blockIdx.x * 256 + threadIdx.x;
    if (e >= E_EDGES) return;
    int d = dst[e];
    int pos = atomicAdd(&cursor[d], 1);
    if (pos < CAP) bucket[d * CAP + pos] = src[e];
}

// Setup with LDS-tiled transpose (coalesced both sides). Blocks 0..63: W1
// (hi+lo); 64..127: Wcat=[Wmu|Wlv] (hi ONLY — gemm2 is single-term now;
// block 64 also fills bcat); rest zero cursor.
__global__ __launch_bounds__(256) void setup_t(
    const float* __restrict__ W1, const float* __restrict__ Wmu,
    const float* __restrict__ Wlv, const float* __restrict__ bmu,
    const float* __restrict__ blv,
    unsigned short* __restrict__ W1h, unsigned short* __restrict__ W1l,
    unsigned short* __restrict__ Wch,
    float* __restrict__ bcat, int* __restrict__ cursor) {
    int b = blockIdx.x, t = threadIdx.x;
    if (b < 128) {
        __shared__ float tile[32][33];          // +1 pad: conflict-free transpose
        int m = b >> 6;                         // 0: W1, 1: Wcat
        int ti = b & 63;
        int k0 = (ti >> 3) * 32, n0 = (ti & 7) * 32;
        int rr = t >> 5, cc = t & 31;           // 8 rows x 32 cols per pass
#pragma unroll
        for (int p = 0; p < 4; ++p) {           // load 32x32 fp32, coalesced in n
            int kk = p * 8 + rr;
            int k = k0 + kk, n = n0 + cc;
            float w;
            if (m == 0) w = W1[k * 256 + n];
            else        w = (n < 128) ? Wmu[k * 128 + n] : Wlv[k * 128 + (n - 128)];
            tile[kk][cc] = w;
        }
        __syncthreads();
#pragma unroll
        for (int p = 0; p < 4; ++p) {           // store [n][k], coalesced in k
            int nn = p * 8 + rr;
            float w = tile[cc][nn];
            unsigned short h = f2bf(w);
            int n = n0 + nn, k = k0 + cc;
            if (m == 0) {
                W1h[n * 256 + k] = h;
                W1l[n * 256 + k] = f2bf(w - bf2f(h));
            } else {
                Wch[n * 256 + k] = h;
            }
        }
        if (b == 64) bcat[t] = (t < 128) ? bmu[t] : blv[t - 128];
    } else {
        int i = (b - 128) * 256 + t;
        if (i < N_NODES) cursor[i] = 0;
    }
}

// MFMA GEMM (layer 1): H[M,256] = X_f32[M,256] @ (Bh+Bl)[256,256], fp32-split
// 3-term. Block = 128 rows x 256 cols, 4 waves 2x2 (each 64 rows x 128 cols).
// [r4-verified best structure: 24 ds_read_b128 -> 96 MFMA per wave per K-step.]
__global__ __launch_bounds__(256, 2) void gemm_mfma(
    const float* __restrict__ A,
    const unsigned short* __restrict__ Bth, const unsigned short* __restrict__ Btl,
    unsigned short* __restrict__ Hout, int M)
{
    __shared__ unsigned short Ash[128 * 32];   // 8 KB
    __shared__ unsigned short Asl[128 * 32];   // 8 KB
    __shared__ unsigned short Bsh[256 * 32];   // 16 KB
    __shared__ unsigned short Bsl[256 * 32];   // 16 KB
    const int t = threadIdx.x;
    const int lane = t & 63, wave = t >> 6;
    const int m_ = lane & 15, q = lane >> 4;
    const int wr = wave >> 1, wc = wave & 1;   // 2x2 wave grid
    const int row0 = blockIdx.x * 128;
    const int sr = t >> 2;                     // staging row 0..63
    const int sc = t & 3;                      // staging chunk 0..3

    f32x4 acc[4][8];
    const f32x4 zf = {0.f, 0.f, 0.f, 0.f};
#pragma unroll
    for (int rs = 0; rs < 4; ++rs)
#pragma unroll
        for (int nt = 0; nt < 8; ++nt) acc[rs][nt] = zf;

    for (int ks = 0; ks < 8; ++ks) {
        const int k0 = ks * 32;
        // global loads: B tile (256n x 32k, hi+lo) and A tile (128 rows fp32)
        bf16x8 gbh[4], gbl[4];
#pragma unroll
        for (int i = 0; i < 4; ++i) {
            int n = sr + i * 64;
            gbh[i] = *(const bf16x8*)(Bth + n * 256 + k0 + sc * 8);
            gbl[i] = *(const bf16x8*)(Btl + n * 256 + k0 + sc * 8);
        }
        float4 ga0[2], ga1[2];
#pragma unroll
        for (int p = 0; p < 2; ++p) {
            int r = row0 + p * 64 + sr; if (r >= M) r = M - 1;
            const float* Xp = A + (size_t)r * 256 + k0 + sc * 8;
            ga0[p] = *(const float4*)Xp;
            ga1[p] = *(const float4*)(Xp + 4);
        }
        __syncthreads();
#pragma unroll
        for (int p = 0; p < 2; ++p) {
            int lr = p * 64 + sr;
            int cc = (sc ^ ((lr >> 1) & 3)) * 8;
            float af[8] = {ga0[p].x, ga0[p].y, ga0[p].z, ga0[p].w,
                           ga1[p].x, ga1[p].y, ga1[p].z, ga1[p].w};
            bf16x8 h, l;
#pragma unroll
            for (int j = 0; j < 8; ++j) {
                unsigned short hh = f2bf(af[j]);
                h[j] = (short)hh;
                l[j] = (short)f2bf(af[j] - bf2f(hh));
            }
            *(bf16x8*)&Ash[lr * 32 + cc] = h;
            *(bf16x8*)&Asl[lr * 32 + cc] = l;
        }
#pragma unroll
        for (int i = 0; i < 4; ++i) {
            int n = sr + i * 64;
            int cc = (sc ^ ((n >> 1) & 3)) * 8;
            *(bf16x8*)&Bsh[n * 32 + cc] = gbh[i];
            *(bf16x8*)&Bsl[n * 32 + cc] = gbl[i];
        }
        __syncthreads();
        // fragment reads + MFMA
        bf16x8 ah[4], al[4];
#pragma unroll
        for (int rs = 0; rs < 4; ++rs) {
            int r = wr * 64 + rs * 16 + m_;
            int cc = (q ^ ((r >> 1) & 3)) * 8;
            ah[rs] = *(const bf16x8*)&Ash[r * 32 + cc];
            al[rs] = *(const bf16x8*)&Asl[r * 32 + cc];
        }
#pragma unroll
        for (int nt = 0; nt < 8; ++nt) {
            int n = wc * 128 + nt * 16 + m_;
            int cr = (q ^ ((n >> 1) & 3)) * 8;
            bf16x8 bh = *(const bf16x8*)&Bsh[n * 32 + cr];
            bf16x8 bl = *(const bf16x8*)&Bsl[n * 32 + cr];
#pragma unroll
            for (int rs = 0; rs < 4; ++rs) {
                acc[rs][nt] = __builtin_amdgcn_mfma_f32_16x16x32_bf16(ah[rs], bh, acc[rs][nt], 0, 0, 0);
                acc[rs][nt] = __builtin_amdgcn_mfma_f32_16x16x32_bf16(ah[rs], bl, acc[rs][nt], 0, 0, 0);
                acc[rs][nt] = __builtin_amdgcn_mfma_f32_16x16x32_bf16(al[rs], bh, acc[rs][nt], 0, 0, 0);
            }
        }
    }
    // epilogue: C/D layout col=lane&15, row=(lane>>4)*4+reg  [m89/m91 verified]
#pragma unroll
    for (int rs = 0; rs < 4; ++rs) {
        int rbase = row0 + wr * 64 + rs * 16 + q * 4;
#pragma unroll
        for (int rr = 0; rr < 4; ++rr) {
            int grow = rbase + rr;
            if (grow >= M) continue;
#pragma unroll
            for (int nt = 0; nt < 8; ++nt) {
                int gcol = wc * 128 + nt * 16 + m_;
                Hout[(size_t)grow * 256 + gcol] = f2bf(acc[rs][nt][rr]);
            }
        }
    }
}

// MFMA GEMM (head): T[M,256] = Z_bf16[M,256] @ Bh[256,256], SINGLE-term
// (A exact bf16; dropped W-lo term adds ~2e-4 error, an order below the
// bf16-T rounding that sets absmax). 128x256 block / 2x2 waves. LDS 24 KB.
__global__ __launch_bounds__(256, 2) void gemm_bf16(
    const unsigned short* __restrict__ A,
    const unsigned short* __restrict__ Bth,
    unsigned short* __restrict__ Tout, int M)
{
    __shared__ unsigned short Ash[128 * 32];   // 8 KB
    __shared__ unsigned short Bsh[256 * 32];   // 16 KB
    const int t = threadIdx.x;
    const int lane = t & 63, wave = t >> 6;
    const int m_ = lane & 15, q = lane >> 4;
    const int wr = wave >> 1, wc = wave & 1;
    const int row0 = blockIdx.x * 128;
    const int sr = t >> 2;
    const int sc = t & 3;

    f32x4 acc[4][8];
    const f32x4 zf = {0.f, 0.f, 0.f, 0.f};
#pragma unroll
    for (int rs = 0; rs < 4; ++rs)
#pragma unroll
        for (int nt = 0; nt < 8; ++nt) acc[rs][nt] = zf;

    for (int ks = 0; ks < 8; ++ks) {
        const int k0 = ks * 32;
        bf16x8 gbh[4];
#pragma unroll
        for (int i = 0; i < 4; ++i) {
            int n = sr + i * 64;
            gbh[i] = *(const bf16x8*)(Bth + n * 256 + k0 + sc * 8);
        }
        bf16x8 gav[2];
#pragma unroll
        for (int p = 0; p < 2; ++p) {
            int r = row0 + p * 64 + sr; if (r >= M) r = M - 1;
            gav[p] = *(const bf16x8*)(A + (size_t)r * 256 + k0 + sc * 8);
        }
        __syncthreads();
#pragma unroll
        for (int p = 0; p < 2; ++p) {
            int lr = p * 64 + sr;
            int cc = (sc ^ ((lr >> 1) & 3)) * 8;
            *(bf16x8*)&Ash[lr * 32 + cc] = gav[p];
        }
#pragma unroll
        for (int i = 0; i < 4; ++i) {
            int n = sr + i * 64;
            int cc = (sc ^ ((n >> 1) & 3)) * 8;
            *(bf16x8*)&Bsh[n * 32 + cc] = gbh[i];
        }
        __syncthreads();
        bf16x8 ah[4];
#pragma unroll
        for (int rs = 0; rs < 4; ++rs) {
            int r = wr * 64 + rs * 16 + m_;
            int cc = (q ^ ((r >> 1) & 3)) * 8;
            ah[rs] = *(const bf16x8*)&Ash[r * 32 + cc];
        }
#pragma unroll
        for (int nt = 0; nt < 8; ++nt) {
            int n = wc * 128 + nt * 16 + m_;
            int cr = (q ^ ((n >> 1) & 3)) * 8;
            bf16x8 bh = *(const bf16x8*)&Bsh[n * 32 + cr];
#pragma unroll
            for (int rs = 0; rs < 4; ++rs) {
                acc[rs][nt] = __builtin_amdgcn_mfma_f32_16x16x32_bf16(ah[rs], bh, acc[rs][nt], 0, 0, 0);
            }
        }
    }
#pragma unroll
    for (int rs = 0; rs < 4; ++rs) {
        int rbase = row0 + wr * 64 + rs * 16 + q * 4;
#pragma unroll
        for (int rr = 0; rr < 4; ++rr) {
            int grow = rbase + rr;
            if (grow >= M) continue;
#pragma unroll
            for (int nt = 0; nt < 8; ++nt) {
                int gcol = wc * 128 + nt * 16 + m_;
                Tout[(size_t)grow * 256 + gcol] = f2bf(acc[rs][nt][rr]);
            }
        }
    }
}

// Two dst nodes per wave; node0 splits the node range across two dispatches
// (~32 us each) so slower kernels surface in the profiler's top-5.
// [gather inner loop verified at the random-gather L2-miss-path floor
// (~3 TB/s, 190 MB) across r1-r6.]
// mode 0: Z = relu(agg + b1) -> bf16.
// mode 1: final heads: [mu|lv] = agg(T) + bcat -> fp32, split at col 128.
__global__ __launch_bounds__(256) void gather_pre(
    const unsigned short* __restrict__ Hs,
    const int* __restrict__ bucket, const int* __restrict__ cnt_,
    const float* __restrict__ bias,
    unsigned short* __restrict__ OutZ,
    float* __restrict__ mu, float* __restrict__ lv, int mode, int node0)
{
    const int lane = threadIdx.x & 63;
    const int hl = lane & 31;                 // lane within half-wave
    const int bb = lane & 32;                 // half-select for shfl index
    const int node = node0 + blockIdx.x * 8 + (threadIdx.x >> 5);
    const int col = hl * 8;                   // 8 bf16 columns per lane
    int raw = cnt_[node];
    float dn = rsqrtf((float)raw + 1.0f);
    int cnt = raw > CAP ? CAP : raw;

    // preload: half-lane j owns edge j (reg0) and edge j+32 (reg1)
    int   s0r = 0, s1r = 0;
    float w0r = 0.f, w1r = 0.f;
    if (hl < cnt) {
        s0r = bucket[node * CAP + hl];
        w0r = rsqrtf((float)cnt_[s0r] + 1.0f) * dn;
    }
    if (hl + 32 < cnt) {
        s1r = bucket[node * CAP + 32 + hl];
        w1r = rsqrtf((float)cnt_[s1r] + 1.0f) * dn;
    }

    // start accumulator with the self-loop term (norm_ii = 1/deg = dn*dn)
    float sl = dn * dn;
    bf16x8 hv = *(const bf16x8*)(Hs + (size_t)node * D + col);
    float a[8];
#pragma unroll
    for (int p = 0; p < 8; ++p) a[p] = bf2f((unsigned short)hv[p]) * sl;

    const int cnt0 = cnt < 32 ? cnt : 32;
    int j = 0;
    for (; j + 3 < cnt0; j += 4) {
        int t0 = __shfl(s0r, bb + j,     64), t1 = __shfl(s0r, bb + j + 1, 64);
        int t2 = __shfl(s0r, bb + j + 2, 64), t3 = __shfl(s0r, bb + j + 3, 64);
        float w0 = __shfl(w0r, bb + j,     64), w1 = __shfl(w0r, bb + j + 1, 64);
        float w2 = __shfl(w0r, bb + j + 2, 64), w3 = __shfl(w0r, bb + j + 3, 64);
        bf16x8 u0 = *(const bf16x8*)(Hs + (size_t)t0 * D + col);
        bf16x8 u1 = *(const bf16x8*)(Hs + (size_t)t1 * D + col);
        bf16x8 u2 = *(const bf16x8*)(Hs + (size_t)t2 * D + col);
        bf16x8 u3 = *(const bf16x8*)(Hs + (size_t)t3 * D + col);
#pragma unroll
        for (int p = 0; p < 8; ++p) a[p] = fmaf(bf2f((unsigned short)u0[p]), w0, a[p]);
#pragma unroll
        for (int p = 0; p < 8; ++p) a[p] = fmaf(bf2f((unsigned short)u1[p]), w1, a[p]);
#pragma unroll
        for (int p = 0; p < 8; ++p) a[p] = fmaf(bf2f((unsigned short)u2[p]), w2, a[p]);
#pragma unroll
        for (int p = 0; p < 8; ++p) a[p] = fmaf(bf2f((unsigned short)u3[p]), w3, a[p]);
    }
    for (; j < cnt0; ++j) {
        int   t0 = __shfl(s0r, bb + j, 64);
        float w0 = __shfl(w0r, bb + j, 64);
        bf16x8 u0 = *(const bf16x8*)(Hs + (size_t)t0 * D + col);
#pragma unroll
        for (int p = 0; p < 8; ++p) a[p] = fmaf(bf2f((unsigned short)u0[p]), w0, a[p]);
    }
    if (cnt > 32) {               // Poisson(16) tail: rare
        for (int j2 = 0; j2 < cnt - 32; ++j2) {
            int   t0 = __shfl(s1r, bb + j2, 64);
            float w0 = __shfl(w1r, bb + j2, 64);
            bf16x8 u0 = *(const bf16x8*)(Hs + (size_t)t0 * D + col);
#pragma unroll
            for (int p = 0; p < 8; ++p) a[p] = fmaf(bf2f((unsigned short)u0[p]), w0, a[p]);
        }
    }

    float4 b0 = *(const float4*)(bias + col);
    float4 b1 = *(const float4*)(bias + col + 4);
    float bf[8] = {b0.x, b0.y, b0.z, b0.w, b1.x, b1.y, b1.z, b1.w};
    if (mode == 0) {
        bf16x8 o;
#pragma unroll
        for (int p = 0; p < 8; ++p) o[p] = (short)f2bf(fmaxf(a[p] + bf[p], 0.f));
        *(bf16x8*)(OutZ + (size_t)node * D + col) = o;
    } else {
        float4 o0, o1;
        o0.x = a[0] + bf[0]; o0.y = a[1] + bf[1];
        o0.z = a[2] + bf[2]; o0.w = a[3] + bf[3];
        o1.x = a[4] + bf[4]; o1.y = a[5] + bf[5];
        o1.z = a[6] + bf[6]; o1.w = a[7] + bf[7];
        // col multiple of 8; 8 cols stay within one head (128 % 8 == 0)
        float* Op = (col < 128) ? (mu + (size_t)node * L + col)
                                : (lv + (size_t)node * L + (col - 128));
        *(float4*)Op = o0;
        *(float4*)(Op + 4) = o1;
    }
}

extern "C" void kernel_launch(void* const* d_in, const int* in_sizes, int n_in,
                              void* d_out, int out_size, void* d_ws, size_t ws_size,
                              hipStream_t stream) {
    const float* x   = (const float*)d_in[0];
    const int*   ei  = (const int*)d_in[1];
    const float* W1  = (const float*)d_in[2];
    const float* b1  = (const float*)d_in[3];
    const float* Wmu = (const float*)d_in[4];
    const float* bmu = (const float*)d_in[5];
    const float* Wlv = (const float*)d_in[6];
    const float* blv = (const float*)d_in[7];
    const int* src = ei;
    const int* dst = ei + E_EDGES;

    const size_t NF = (size_t)N_NODES * D;  // 12.8M
    unsigned short* Hb = (unsigned short*)d_ws;   // [N,256] bf16
    unsigned short* Z  = Hb + NF;                 // [N,256] bf16
    unsigned short* T  = Z + NF;                  // [N,256] bf16 = Z @ [Wmu|Wlv]
    unsigned short* W1h = T + NF;
    unsigned short* W1l = W1h + 65536;
    unsigned short* Wch = W1l + 65536;
    unsigned short* Wcl = Wch + 65536;            // (unused since r7)
    float* bcat = (float*)(Wcl + 65536);
    int* cursor = (int*)(bcat + 256);
    int* bucket = cursor + N_NODES;          // [N*CAP]
    float* mu = (float*)d_out;
    float* lv = mu + (size_t)N_NODES * L;

    // setup: tiled weight transpose/split + cursor zeroing in one launch
    setup_t<<<128 + (N_NODES + 255) / 256, 256, 0, stream>>>(
        W1, Wmu, Wlv, bmu, blv, W1h, W1l, Wch, bcat, cursor);
    // graph build: one atomic pass, degrees land in cursor
    fill_fixed<<<(E_EDGES + 255) / 256, 256, 0, stream>>>(src, dst, cursor, bucket);

    const int gemm_blocks = (N_NODES + 127) / 128;   // 391
    const int gat_blocks  = (N_NODES / 2) / 8;       // 3125 per half
    // layer 1: H = X@W1 (bf16 out)
    gemm_mfma<<<gemm_blocks, 256, 0, stream>>>(x, W1h, W1l, Hb, N_NODES);
    // Z = relu(P·H + b1)   (two halves for profiler visibility)
    gather_pre<<<gat_blocks, 256, 0, stream>>>(Hb, bucket, cursor, b1,
                                               Z, nullptr, nullptr, 0, 0);
    gather_pre<<<gat_blocks, 256, 0, stream>>>(Hb, bucket, cursor, b1,
                                               Z, nullptr, nullptr, 0, N_NODES / 2);
    // T = Z @ Wc_hi  (bf16; P commutes with right-multiplication)
    gemm_bf16<<<gemm_blocks, 256, 0, stream>>>(Z, Wch, T, N_NODES);
    // [mu|lv] = P·T + [bmu|blv]  (fp32, direct to output)
    gather_pre<<<gat_blocks, 256, 0, stream>>>(T, bucket, cursor, bcat,
                                               nullptr, mu, lv, 1, 0);
    gather_pre<<<gat_blocks, 256, 0, stream>>>(T, bucket, cursor, bcat,
                                               nullptr, mu, lv, 1, N_NODES / 2);
}

// Round 8
// 313.468 us; speedup vs baseline: 1.0457x; 1.0216x over previous
//
#include <hip/hip_runtime.h>

#define N_NODES 50000
#define E_EDGES 800000
#define D 256
#define L 128
#define CAP 64   // max in-degree bucket capacity; Poisson(16) tail => P(overflow) ~ 1e-19

typedef __attribute__((ext_vector_type(8))) short bf16x8;
typedef __attribute__((ext_vector_type(4))) float f32x4;

__device__ __forceinline__ float bf2f(unsigned short u) {
    union { unsigned int i; float f; } v; v.i = ((unsigned int)u) << 16; return v.f;
}
__device__ __forceinline__ unsigned short f2bf(float f) {  // round-to-nearest-even
    union { float f; unsigned int i; } v; v.f = f;
    unsigned int r = v.i + 0x7fffu + ((v.i >> 16) & 1u);
    return (unsigned short)(r >> 16);
}

// Setup with LDS-tiled transpose (coalesced both sides). Blocks 0..63: W1
// (hi+lo); 64..127: Wcat=[Wmu|Wlv] (hi only — gemm2 is single-term;
// block 64 also fills bcat); rest zero cursor.
__global__ __launch_bounds__(256) void setup_t(
    const float* __restrict__ W1, const float* __restrict__ Wmu,
    const float* __restrict__ Wlv, const float* __restrict__ bmu,
    const float* __restrict__ blv,
    unsigned short* __restrict__ W1h, unsigned short* __restrict__ W1l,
    unsigned short* __restrict__ Wch,
    float* __restrict__ bcat, int* __restrict__ cursor) {
    int b = blockIdx.x, t = threadIdx.x;
    if (b < 128) {
        __shared__ float tile[32][33];          // +1 pad: conflict-free transpose
        int m = b >> 6;                         // 0: W1, 1: Wcat
        int ti = b & 63;
        int k0 = (ti >> 3) * 32, n0 = (ti & 7) * 32;
        int rr = t >> 5, cc = t & 31;           // 8 rows x 32 cols per pass
#pragma unroll
        for (int p = 0; p < 4; ++p) {           // load 32x32 fp32, coalesced in n
            int kk = p * 8 + rr;
            int k = k0 + kk, n = n0 + cc;
            float w;
            if (m == 0) w = W1[k * 256 + n];
            else        w = (n < 128) ? Wmu[k * 128 + n] : Wlv[k * 128 + (n - 128)];
            tile[kk][cc] = w;
        }
        __syncthreads();
#pragma unroll
        for (int p = 0; p < 4; ++p) {           // store [n][k], coalesced in k
            int nn = p * 8 + rr;
            float w = tile[cc][nn];
            unsigned short h = f2bf(w);
            int n = n0 + nn, k = k0 + cc;
            if (m == 0) {
                W1h[n * 256 + k] = h;
                W1l[n * 256 + k] = f2bf(w - bf2f(h));
            } else {
                Wch[n * 256 + k] = h;
            }
        }
        if (b == 64) bcat[t] = (t < 128) ? bmu[t] : blv[t - 128];
    } else {
        int i = (b - 128) * 256 + t;
        if (i < N_NODES) cursor[i] = 0;
    }
}

// FUSED: layer-1 GEMM + bucket build, co-scheduled in one grid.
// Blocks with bid%9==0 (exactly 391) run a 128-row GEMM tile (r4-verified
// structure); the other 3125 blocks each process 256 edges of the atomic
// bucket build. The fill blocks are memory-latency-bound (0.4% VALU — r7
// counters), so their stalls hide under co-resident GEMM waves.
// Bucket entries are ushort (src < 65536): one node's CAP=64 bucket = one
// 128 B line, halving the partial-line write-back amplification.
__global__ __launch_bounds__(256, 2) void gemm1_fill(
    const float* __restrict__ A,
    const unsigned short* __restrict__ Bth, const unsigned short* __restrict__ Btl,
    unsigned short* __restrict__ Hout, int M,
    const int* __restrict__ src, const int* __restrict__ dst,
    int* __restrict__ cursor, unsigned short* __restrict__ bucket)
{
    __shared__ unsigned short Ash[128 * 32];   // 8 KB
    __shared__ unsigned short Asl[128 * 32];   // 8 KB
    __shared__ unsigned short Bsh[256 * 32];   // 16 KB
    __shared__ unsigned short Bsl[256 * 32];   // 16 KB
    const int bid = blockIdx.x;
    const int qb = bid / 9, rb = bid - qb * 9;
    const int t = threadIdx.x;

    if (rb != 0) {
        // ---- fill role: 256 edges ----
        int e = (bid - qb - 1) * 256 + t;      // bijective onto [0, 800000)
        if (e < E_EDGES) {
            int d = dst[e];
            int pos = atomicAdd(&cursor[d], 1);
            if (pos < CAP) bucket[d * CAP + pos] = (unsigned short)src[e];
        }
        return;
    }

    // ---- GEMM role: tile qb (0..390) ----
    const int lane = t & 63, wave = t >> 6;
    const int m_ = lane & 15, q = lane >> 4;
    const int wr = wave >> 1, wc = wave & 1;   // 2x2 wave grid
    const int row0 = qb * 128;
    const int sr = t >> 2;                     // staging row 0..63
    const int sc = t & 3;                      // staging chunk 0..3

    f32x4 acc[4][8];
    const f32x4 zf = {0.f, 0.f, 0.f, 0.f};
#pragma unroll
    for (int rs = 0; rs < 4; ++rs)
#pragma unroll
        for (int nt = 0; nt < 8; ++nt) acc[rs][nt] = zf;

    for (int ks = 0; ks < 8; ++ks) {
        const int k0 = ks * 32;
        bf16x8 gbh[4], gbl[4];
#pragma unroll
        for (int i = 0; i < 4; ++i) {
            int n = sr + i * 64;
            gbh[i] = *(const bf16x8*)(Bth + n * 256 + k0 + sc * 8);
            gbl[i] = *(const bf16x8*)(Btl + n * 256 + k0 + sc * 8);
        }
        float4 ga0[2], ga1[2];
#pragma unroll
        for (int p = 0; p < 2; ++p) {
            int r = row0 + p * 64 + sr; if (r >= M) r = M - 1;
            const float* Xp = A + (size_t)r * 256 + k0 + sc * 8;
            ga0[p] = *(const float4*)Xp;
            ga1[p] = *(const float4*)(Xp + 4);
        }
        __syncthreads();
#pragma unroll
        for (int p = 0; p < 2; ++p) {
            int lr = p * 64 + sr;
            int cc = (sc ^ ((lr >> 1) & 3)) * 8;
            float af[8] = {ga0[p].x, ga0[p].y, ga0[p].z, ga0[p].w,
                           ga1[p].x, ga1[p].y, ga1[p].z, ga1[p].w};
            bf16x8 h, l;
#pragma unroll
            for (int j = 0; j < 8; ++j) {
                unsigned short hh = f2bf(af[j]);
                h[j] = (short)hh;
                l[j] = (short)f2bf(af[j] - bf2f(hh));
            }
            *(bf16x8*)&Ash[lr * 32 + cc] = h;
            *(bf16x8*)&Asl[lr * 32 + cc] = l;
        }
#pragma unroll
        for (int i = 0; i < 4; ++i) {
            int n = sr + i * 64;
            int cc = (sc ^ ((n >> 1) & 3)) * 8;
            *(bf16x8*)&Bsh[n * 32 + cc] = gbh[i];
            *(bf16x8*)&Bsl[n * 32 + cc] = gbl[i];
        }
        __syncthreads();
        bf16x8 ah[4], al[4];
#pragma unroll
        for (int rs = 0; rs < 4; ++rs) {
            int r = wr * 64 + rs * 16 + m_;
            int cc = (q ^ ((r >> 1) & 3)) * 8;
            ah[rs] = *(const bf16x8*)&Ash[r * 32 + cc];
            al[rs] = *(const bf16x8*)&Asl[r * 32 + cc];
        }
#pragma unroll
        for (int nt = 0; nt < 8; ++nt) {
            int n = wc * 128 + nt * 16 + m_;
            int cr = (q ^ ((n >> 1) & 3)) * 8;
            bf16x8 bh = *(const bf16x8*)&Bsh[n * 32 + cr];
            bf16x8 bl = *(const bf16x8*)&Bsl[n * 32 + cr];
#pragma unroll
            for (int rs = 0; rs < 4; ++rs) {
                acc[rs][nt] = __builtin_amdgcn_mfma_f32_16x16x32_bf16(ah[rs], bh, acc[rs][nt], 0, 0, 0);
                acc[rs][nt] = __builtin_amdgcn_mfma_f32_16x16x32_bf16(ah[rs], bl, acc[rs][nt], 0, 0, 0);
                acc[rs][nt] = __builtin_amdgcn_mfma_f32_16x16x32_bf16(al[rs], bh, acc[rs][nt], 0, 0, 0);
            }
        }
    }
    // epilogue: C/D layout col=lane&15, row=(lane>>4)*4+reg  [m89/m91 verified]
#pragma unroll
    for (int rs = 0; rs < 4; ++rs) {
        int rbase = row0 + wr * 64 + rs * 16 + q * 4;
#pragma unroll
        for (int rr = 0; rr < 4; ++rr) {
            int grow = rbase + rr;
            if (grow >= M) continue;
#pragma unroll
            for (int nt = 0; nt < 8; ++nt) {
                int gcol = wc * 128 + nt * 16 + m_;
                Hout[(size_t)grow * 256 + gcol] = f2bf(acc[rs][nt][rr]);
            }
        }
    }
}

// MFMA GEMM (head): T[M,256] = Z_bf16[M,256] @ Bh[256,256], single-term
// (r7-verified: dropped W-lo term leaves absmax bit-identical).
__global__ __launch_bounds__(256, 2) void gemm_bf16(
    const unsigned short* __restrict__ A,
    const unsigned short* __restrict__ Bth,
    unsigned short* __restrict__ Tout, int M)
{
    __shared__ unsigned short Ash[128 * 32];   // 8 KB
    __shared__ unsigned short Bsh[256 * 32];   // 16 KB
    const int t = threadIdx.x;
    const int lane = t & 63, wave = t >> 6;
    const int m_ = lane & 15, q = lane >> 4;
    const int wr = wave >> 1, wc = wave & 1;
    const int row0 = blockIdx.x * 128;
    const int sr = t >> 2;
    const int sc = t & 3;

    f32x4 acc[4][8];
    const f32x4 zf = {0.f, 0.f, 0.f, 0.f};
#pragma unroll
    for (int rs = 0; rs < 4; ++rs)
#pragma unroll
        for (int nt = 0; nt < 8; ++nt) acc[rs][nt] = zf;

    for (int ks = 0; ks < 8; ++ks) {
        const int k0 = ks * 32;
        bf16x8 gbh[4];
#pragma unroll
        for (int i = 0; i < 4; ++i) {
            int n = sr + i * 64;
            gbh[i] = *(const bf16x8*)(Bth + n * 256 + k0 + sc * 8);
        }
        bf16x8 gav[2];
#pragma unroll
        for (int p = 0; p < 2; ++p) {
            int r = row0 + p * 64 + sr; if (r >= M) r = M - 1;
            gav[p] = *(const bf16x8*)(A + (size_t)r * 256 + k0 + sc * 8);
        }
        __syncthreads();
#pragma unroll
        for (int p = 0; p < 2; ++p) {
            int lr = p * 64 + sr;
            int cc = (sc ^ ((lr >> 1) & 3)) * 8;
            *(bf16x8*)&Ash[lr * 32 + cc] = gav[p];
        }
#pragma unroll
        for (int i = 0; i < 4; ++i) {
            int n = sr + i * 64;
            int cc = (sc ^ ((n >> 1) & 3)) * 8;
            *(bf16x8*)&Bsh[n * 32 + cc] = gbh[i];
        }
        __syncthreads();
        bf16x8 ah[4];
#pragma unroll
        for (int rs = 0; rs < 4; ++rs) {
            int r = wr * 64 + rs * 16 + m_;
            int cc = (q ^ ((r >> 1) & 3)) * 8;
            ah[rs] = *(const bf16x8*)&Ash[r * 32 + cc];
        }
#pragma unroll
        for (int nt = 0; nt < 8; ++nt) {
            int n = wc * 128 + nt * 16 + m_;
            int cr = (q ^ ((n >> 1) & 3)) * 8;
            bf16x8 bh = *(const bf16x8*)&Bsh[n * 32 + cr];
#pragma unroll
            for (int rs = 0; rs < 4; ++rs) {
                acc[rs][nt] = __builtin_amdgcn_mfma_f32_16x16x32_bf16(ah[rs], bh, acc[rs][nt], 0, 0, 0);
            }
        }
    }
#pragma unroll
    for (int rs = 0; rs < 4; ++rs) {
        int rbase = row0 + wr * 64 + rs * 16 + q * 4;
#pragma unroll
        for (int rr = 0; rr < 4; ++rr) {
            int grow = rbase + rr;
            if (grow >= M) continue;
#pragma unroll
            for (int nt = 0; nt < 8; ++nt) {
                int gcol = wc * 128 + nt * 16 + m_;
                Tout[(size_t)grow * 256 + gcol] = f2bf(acc[rs][nt][rr]);
            }
        }
    }
}

// Two dst nodes per wave; node0 splits the node range across two dispatches
// (~32 us each, keeps slower kernels visible in the profiler's top-5).
// [inner loop verified at the random-gather L2-miss-path floor (~3 TB/s)
// across r1-r7.] Bucket entries are ushort.
// mode 0: Z = relu(agg + b1) -> bf16.
// mode 1: final heads: [mu|lv] = agg(T) + bcat -> fp32, split at col 128.
__global__ __launch_bounds__(256) void gather_pre(
    const unsigned short* __restrict__ Hs,
    const unsigned short* __restrict__ bucket, const int* __restrict__ cnt_,
    const float* __restrict__ bias,
    unsigned short* __restrict__ OutZ,
    float* __restrict__ mu, float* __restrict__ lv, int mode, int node0)
{
    const int lane = threadIdx.x & 63;
    const int hl = lane & 31;                 // lane within half-wave
    const int bb = lane & 32;                 // half-select for shfl index
    const int node = node0 + blockIdx.x * 8 + (threadIdx.x >> 5);
    const int col = hl * 8;                   // 8 bf16 columns per lane
    int raw = cnt_[node];
    float dn = rsqrtf((float)raw + 1.0f);
    int cnt = raw > CAP ? CAP : raw;

    // preload: half-lane j owns edge j (reg0) and edge j+32 (reg1)
    int   s0r = 0, s1r = 0;
    float w0r = 0.f, w1r = 0.f;
    if (hl < cnt) {
        s0r = (int)bucket[node * CAP + hl];
        w0r = rsqrtf((float)cnt_[s0r] + 1.0f) * dn;
    }
    if (hl + 32 < cnt) {
        s1r = (int)bucket[node * CAP + 32 + hl];
        w1r = rsqrtf((float)cnt_[s1r] + 1.0f) * dn;
    }

    // start accumulator with the self-loop term (norm_ii = 1/deg = dn*dn)
    float sl = dn * dn;
    bf16x8 hv = *(const bf16x8*)(Hs + (size_t)node * D + col);
    float a[8];
#pragma unroll
    for (int p = 0; p < 8; ++p) a[p] = bf2f((unsigned short)hv[p]) * sl;

    const int cnt0 = cnt < 32 ? cnt : 32;
    int j = 0;
    for (; j + 3 < cnt0; j += 4) {
        int t0 = __shfl(s0r, bb + j,     64), t1 = __shfl(s0r, bb + j + 1, 64);
        int t2 = __shfl(s0r, bb + j + 2, 64), t3 = __shfl(s0r, bb + j + 3, 64);
        float w0 = __shfl(w0r, bb + j,     64), w1 = __shfl(w0r, bb + j + 1, 64);
        float w2 = __shfl(w0r, bb + j + 2, 64), w3 = __shfl(w0r, bb + j + 3, 64);
        bf16x8 u0 = *(const bf16x8*)(Hs + (size_t)t0 * D + col);
        bf16x8 u1 = *(const bf16x8*)(Hs + (size_t)t1 * D + col);
        bf16x8 u2 = *(const bf16x8*)(Hs + (size_t)t2 * D + col);
        bf16x8 u3 = *(const bf16x8*)(Hs + (size_t)t3 * D + col);
#pragma unroll
        for (int p = 0; p < 8; ++p) a[p] = fmaf(bf2f((unsigned short)u0[p]), w0, a[p]);
#pragma unroll
        for (int p = 0; p < 8; ++p) a[p] = fmaf(bf2f((unsigned short)u1[p]), w1, a[p]);
#pragma unroll
        for (int p = 0; p < 8; ++p) a[p] = fmaf(bf2f((unsigned short)u2[p]), w2, a[p]);
#pragma unroll
        for (int p = 0; p < 8; ++p) a[p] = fmaf(bf2f((unsigned short)u3[p]), w3, a[p]);
    }
    for (; j < cnt0; ++j) {
        int   t0 = __shfl(s0r, bb + j, 64);
        float w0 = __shfl(w0r, bb + j, 64);
        bf16x8 u0 = *(const bf16x8*)(Hs + (size_t)t0 * D + col);
#pragma unroll
        for (int p = 0; p < 8; ++p) a[p] = fmaf(bf2f((unsigned short)u0[p]), w0, a[p]);
    }
    if (cnt > 32) {               // Poisson(16) tail: rare
        for (int j2 = 0; j2 < cnt - 32; ++j2) {
            int   t0 = __shfl(s1r, bb + j2, 64);
            float w0 = __shfl(w1r, bb + j2, 64);
            bf16x8 u0 = *(const bf16x8*)(Hs + (size_t)t0 * D + col);
#pragma unroll
            for (int p = 0; p < 8; ++p) a[p] = fmaf(bf2f((unsigned short)u0[p]), w0, a[p]);
        }
    }

    float4 b0 = *(const float4*)(bias + col);
    float4 b1 = *(const float4*)(bias + col + 4);
    float bf[8] = {b0.x, b0.y, b0.z, b0.w, b1.x, b1.y, b1.z, b1.w};
    if (mode == 0) {
        bf16x8 o;
#pragma unroll
        for (int p = 0; p < 8; ++p) o[p] = (short)f2bf(fmaxf(a[p] + bf[p], 0.f));
        *(bf16x8*)(OutZ + (size_t)node * D + col) = o;
    } else {
        float4 o0, o1;
        o0.x = a[0] + bf[0]; o0.y = a[1] + bf[1];
        o0.z = a[2] + bf[2]; o0.w = a[3] + bf[3];
        o1.x = a[4] + bf[4]; o1.y = a[5] + bf[5];
        o1.z = a[6] + bf[6]; o1.w = a[7] + bf[7];
        // col multiple of 8; 8 cols stay within one head (128 % 8 == 0)
        float* Op = (col < 128) ? (mu + (size_t)node * L + col)
                                : (lv + (size_t)node * L + (col - 128));
        *(float4*)Op = o0;
        *(float4*)(Op + 4) = o1;
    }
}

extern "C" void kernel_launch(void* const* d_in, const int* in_sizes, int n_in,
                              void* d_out, int out_size, void* d_ws, size_t ws_size,
                              hipStream_t stream) {
    const float* x   = (const float*)d_in[0];
    const int*   ei  = (const int*)d_in[1];
    const float* W1  = (const float*)d_in[2];
    const float* b1  = (const float*)d_in[3];
    const float* Wmu = (const float*)d_in[4];
    const float* bmu = (const float*)d_in[5];
    const float* Wlv = (const float*)d_in[6];
    const float* blv = (const float*)d_in[7];
    const int* src = ei;
    const int* dst = ei + E_EDGES;

    const size_t NF = (size_t)N_NODES * D;  // 12.8M
    unsigned short* Hb = (unsigned short*)d_ws;   // [N,256] bf16
    unsigned short* Z  = Hb + NF;                 // [N,256] bf16
    unsigned short* T  = Z + NF;                  // [N,256] bf16 = Z @ Wc_hi
    unsigned short* W1h = T + NF;
    unsigned short* W1l = W1h + 65536;
    unsigned short* Wch = W1l + 65536;
    unsigned short* bucket = Wch + 65536;         // [N*CAP] ushort (6.4 MB)
    float* bcat = (float*)(bucket + (size_t)N_NODES * CAP);
    int* cursor = (int*)(bcat + 256);
    float* mu = (float*)d_out;
    float* lv = mu + (size_t)N_NODES * L;

    // setup: tiled weight transpose/split + cursor zeroing in one launch
    setup_t<<<128 + (N_NODES + 255) / 256, 256, 0, stream>>>(
        W1, Wmu, Wlv, bmu, blv, W1h, W1l, Wch, bcat, cursor);

    // fused: H = X@W1 (391 GEMM blocks) + bucket build (3125 fill blocks),
    // interleaved via bid%9 so fill latency hides under GEMM waves
    gemm1_fill<<<3516, 256, 0, stream>>>(x, W1h, W1l, Hb, N_NODES,
                                         src, dst, cursor, bucket);

    const int gemm_blocks = (N_NODES + 127) / 128;   // 391
    const int gat_blocks  = (N_NODES / 2) / 8;       // 3125 per half
    // Z = relu(P·H + b1)   (two halves for profiler visibility)
    gather_pre<<<gat_blocks, 256, 0, stream>>>(Hb, bucket, cursor, b1,
                                               Z, nullptr, nullptr, 0, 0);
    gather_pre<<<gat_blocks, 256, 0, stream>>>(Hb, bucket, cursor, b1,
                                               Z, nullptr, nullptr, 0, N_NODES / 2);
    // T = Z @ Wc_hi  (bf16; P commutes with right-multiplication)
    gemm_bf16<<<gemm_blocks, 256, 0, stream>>>(Z, Wch, T, N_NODES);
    // [mu|lv] = P·T + [bmu|blv]  (fp32, direct to output)
    gather_pre<<<gat_blocks, 256, 0, stream>>>(T, bucket, cursor, bcat,
                                               nullptr, mu, lv, 1, 0);
    gather_pre<<<gat_blocks, 256, 0, stream>>>(T, bucket, cursor, bcat,
                                               nullptr, mu, lv, 1, N_NODES / 2);
}